// Round 7
// baseline (28878.827 us; speedup 1.0000x reference)
//
#include <hip/hip_runtime.h>

// 2-layer biLSTM, B=128 T=256 IN=64 H=256, + fc to [128,1].
// SYNC-FREE recurrence: one 1024-thread WG owns a whole (direction, 2-batch)
// group; h recurrence lives in LDS (ping-pong), K-split 4 across lanes with
// shfl allreduce. W_hh pinned in VGPRs. Layer-1 x-GEMM (xg = out0@W_ih+bias)
// is hoisted out as a parallel fp32 GEMM, time-chunked to bound workspace.
// No atomics, no polling, no cross-WG coupling -> deterministic.

constexpr int B_ = 128, T_ = 256, IN_ = 64, H_ = 256;
constexpr int BB  = 2;            // batch rows per recurrence WG
constexpr int NG  = B_ / BB;      // 64 groups per direction
constexpr int RTH = 1024;         // recurrence WG size

#define KEEP_REG(x) asm volatile("" : "+v"(x))

__device__ __forceinline__ float sigmoid_(float x) { return 1.f / (1.f + __expf(-x)); }
__device__ __forceinline__ float tanh_(float x)    { return 1.f - 2.f / (1.f + __expf(2.f * x)); }

// ---------------- Layer 0: recurrence with inline x (K=64) ----------------
__global__ __launch_bounds__(RTH, 1)
void l0_recur(const float* __restrict__ x,
              const float* __restrict__ wih_f, const float* __restrict__ whh_f,
              const float* __restrict__ bih_f, const float* __restrict__ bhh_f,
              const float* __restrict__ wih_b, const float* __restrict__ whh_b,
              const float* __restrict__ bih_b, const float* __restrict__ bhh_b,
              float* __restrict__ out0)                  // [T][B][512]
{
  const int d   = blockIdx.x >> 6;
  const int bb  = blockIdx.x & 63;
  const int tid = threadIdx.x;
  const int wave = tid >> 6, lane = tid & 63;
  const int ks = lane >> 4;            // 0..3 K-slice (partners at lane^16,^32)
  const int j  = wave * 16 + (lane & 15);   // hidden dim 0..255

  const float* wih = d ? wih_b : wih_f;
  const float* whh = d ? whh_b : whh_f;
  const float* bih = d ? bih_b : bih_f;
  const float* bhh = d ? bhh_b : bhh_f;

  float wr[4][64], wx[4][16], br[4];
  #pragma unroll
  for (int g = 0; g < 4; ++g) {
    const long row = g * 256 + j;
    #pragma unroll
    for (int i4 = 0; i4 < 16; ++i4) {
      const float4 w4 = *(const float4*)&whh[row * 256 + ks * 64 + i4 * 4];
      wr[g][i4*4+0] = w4.x; wr[g][i4*4+1] = w4.y;
      wr[g][i4*4+2] = w4.z; wr[g][i4*4+3] = w4.w;
    }
    #pragma unroll
    for (int i4 = 0; i4 < 4; ++i4) {
      const float4 w4 = *(const float4*)&wih[row * 64 + ks * 16 + i4 * 4];
      wx[g][i4*4+0] = w4.x; wx[g][i4*4+1] = w4.y;
      wx[g][i4*4+2] = w4.z; wx[g][i4*4+3] = w4.w;
    }
    br[g] = bih[row] + bhh[row];
  }
  #pragma unroll
  for (int g = 0; g < 4; ++g) {
    #pragma unroll
    for (int i = 0; i < 64; ++i) KEEP_REG(wr[g][i]);
    #pragma unroll
    for (int i = 0; i < 16; ++i) KEEP_REG(wx[g][i]);
  }

  __shared__ alignas(16) float hbuf[2][BB][256];
  __shared__ alignas(16) float xbuf[2][BB][64];

  if (tid < BB * 256) hbuf[1][tid >> 8][tid & 255] = 0.f;
  if (tid < BB * 16) {
    const int b = tid >> 4, q = tid & 15;
    const int tt0 = d ? (T_ - 1) : 0;
    *(float4*)&xbuf[0][b][q * 4] =
        *(const float4*)&x[((long)(bb * BB + b) * T_ + tt0) * 64 + q * 4];
  }
  float cs[BB] = {0.f, 0.f};
  __syncthreads();

  for (int t = 0; t < T_; ++t) {
    const int tt = d ? (T_ - 1 - t) : t;
    const int rp = (t + 1) & 1, wp = t & 1;

    // prefetch x(t+1) early (latency hides under the FMA block)
    float4 xpre;
    const bool pf = (t + 1 < T_) && (tid < BB * 16);
    if (pf) {
      const int b = tid >> 4, q = tid & 15;
      const int ttn = d ? (T_ - 2 - t) : (t + 1);
      xpre = *(const float4*)&x[((long)(bb * BB + b) * T_ + ttn) * 64 + q * 4];
    }

    float acc[BB][4] = {};
    #pragma unroll
    for (int b = 0; b < BB; ++b) {
      #pragma unroll
      for (int i4 = 0; i4 < 4; ++i4) {          // x part (16 per gate)
        const float4 xv = *(const float4*)&xbuf[wp][b][ks * 16 + i4 * 4];
        #pragma unroll
        for (int g = 0; g < 4; ++g) {
          acc[b][g] = fmaf(xv.x, wx[g][i4*4+0], acc[b][g]);
          acc[b][g] = fmaf(xv.y, wx[g][i4*4+1], acc[b][g]);
          acc[b][g] = fmaf(xv.z, wx[g][i4*4+2], acc[b][g]);
          acc[b][g] = fmaf(xv.w, wx[g][i4*4+3], acc[b][g]);
        }
      }
      #pragma unroll
      for (int i4 = 0; i4 < 16; ++i4) {         // h part (64 per gate)
        const float4 hv = *(const float4*)&hbuf[rp][b][ks * 64 + i4 * 4];
        #pragma unroll
        for (int g = 0; g < 4; ++g) {
          acc[b][g] = fmaf(hv.x, wr[g][i4*4+0], acc[b][g]);
          acc[b][g] = fmaf(hv.y, wr[g][i4*4+1], acc[b][g]);
          acc[b][g] = fmaf(hv.z, wr[g][i4*4+2], acc[b][g]);
          acc[b][g] = fmaf(hv.w, wr[g][i4*4+3], acc[b][g]);
        }
      }
    }
    #pragma unroll
    for (int b = 0; b < BB; ++b)
      #pragma unroll
      for (int g = 0; g < 4; ++g) {
        float a = acc[b][g];
        a += __shfl_xor(a, 16, 64);
        a += __shfl_xor(a, 32, 64);
        acc[b][g] = a + br[g];
      }
    #pragma unroll
    for (int b = 0; b < BB; ++b) {
      const float ig = sigmoid_(acc[b][0]);
      const float fg = sigmoid_(acc[b][1]);
      const float gv = tanh_(acc[b][2]);
      const float og = sigmoid_(acc[b][3]);
      cs[b] = fg * cs[b] + ig * gv;
      const float hv = og * tanh_(cs[b]);
      if (ks == 0) {
        hbuf[wp][b][j] = hv;
        out0[((long)tt * B_ + bb * BB + b) * 512 + d * 256 + j] = hv;
      }
    }
    if (pf) {
      const int b = tid >> 4, q = tid & 15;
      *(float4*)&xbuf[rp][b][q * 4] = xpre;
    }
    __syncthreads();
  }
}

// ---------------- Layer 1: recurrence (xg precomputed, bias folded) -------
__global__ __launch_bounds__(RTH, 1)
void l1_recur(const float* __restrict__ whh,   // direction-selected [1024][256]
              const float* __restrict__ xg,    // [nsteps][B][1024]
              float* __restrict__ hstate, float* __restrict__ cstate,  // [B][256]
              float* __restrict__ hfinal,      // pre-offset, stride 512
              int nsteps, int first, int writeState, int lastWrite)
{
  const int bb  = blockIdx.x;
  const int tid = threadIdx.x;
  const int wave = tid >> 6, lane = tid & 63;
  const int ks = lane >> 4;
  const int j  = wave * 16 + (lane & 15);

  float wr[4][64];
  #pragma unroll
  for (int g = 0; g < 4; ++g) {
    const long row = g * 256 + j;
    #pragma unroll
    for (int i4 = 0; i4 < 16; ++i4) {
      const float4 w4 = *(const float4*)&whh[row * 256 + ks * 64 + i4 * 4];
      wr[g][i4*4+0] = w4.x; wr[g][i4*4+1] = w4.y;
      wr[g][i4*4+2] = w4.z; wr[g][i4*4+3] = w4.w;
    }
  }
  #pragma unroll
  for (int g = 0; g < 4; ++g)
    #pragma unroll
    for (int i = 0; i < 64; ++i) KEEP_REG(wr[g][i]);

  __shared__ alignas(16) float hbuf[2][BB][256];
  if (tid < BB * 256) {
    const int b = tid >> 8, jj = tid & 255;
    hbuf[1][b][jj] = first ? 0.f : hstate[(long)(bb * BB + b) * 256 + jj];
  }
  float cs[BB];
  #pragma unroll
  for (int b = 0; b < BB; ++b)
    cs[b] = first ? 0.f : cstate[(long)(bb * BB + b) * 256 + j];

  float xgv[BB], xgn[BB];
  #pragma unroll
  for (int b = 0; b < BB; ++b)
    xgv[b] = xg[(long)(bb * BB + b) * 1024 + ks * 256 + j];
  __syncthreads();

  for (int t = 0; t < nsteps; ++t) {
    const int rp = (t + 1) & 1, wp = t & 1;
    const int tn = (t + 1 < nsteps) ? t + 1 : t;
    #pragma unroll
    for (int b = 0; b < BB; ++b)      // prefetch next step's xg
      xgn[b] = xg[((long)tn * B_ + bb * BB + b) * 1024 + ks * 256 + j];

    float acc[BB][4];
    #pragma unroll
    for (int b = 0; b < BB; ++b)
      #pragma unroll
      for (int g = 0; g < 4; ++g)
        acc[b][g] = (g == ks) ? xgv[b] : 0.f;   // xg enters via its gate slot

    #pragma unroll
    for (int b = 0; b < BB; ++b) {
      #pragma unroll
      for (int i4 = 0; i4 < 16; ++i4) {
        const float4 hv = *(const float4*)&hbuf[rp][b][ks * 64 + i4 * 4];
        #pragma unroll
        for (int g = 0; g < 4; ++g) {
          acc[b][g] = fmaf(hv.x, wr[g][i4*4+0], acc[b][g]);
          acc[b][g] = fmaf(hv.y, wr[g][i4*4+1], acc[b][g]);
          acc[b][g] = fmaf(hv.z, wr[g][i4*4+2], acc[b][g]);
          acc[b][g] = fmaf(hv.w, wr[g][i4*4+3], acc[b][g]);
        }
      }
    }
    #pragma unroll
    for (int b = 0; b < BB; ++b)
      #pragma unroll
      for (int g = 0; g < 4; ++g) {
        float a = acc[b][g];
        a += __shfl_xor(a, 16, 64);
        a += __shfl_xor(a, 32, 64);
        acc[b][g] = a;                 // bias already inside xg
      }
    #pragma unroll
    for (int b = 0; b < BB; ++b) {
      const float ig = sigmoid_(acc[b][0]);
      const float fg = sigmoid_(acc[b][1]);
      const float gv = tanh_(acc[b][2]);
      const float og = sigmoid_(acc[b][3]);
      cs[b] = fg * cs[b] + ig * gv;
      const float hv = og * tanh_(cs[b]);
      if (ks == 0) {
        hbuf[wp][b][j] = hv;
        if (lastWrite && t == nsteps - 1)
          hfinal[(long)(bb * BB + b) * 512 + j] = hv;
        if (writeState && t == nsteps - 1) {
          hstate[(long)(bb * BB + b) * 256 + j] = hv;
          cstate[(long)(bb * BB + b) * 256 + j] = cs[b];
        }
      }
    }
    #pragma unroll
    for (int b = 0; b < BB; ++b) xgv[b] = xgn[b];
    __syncthreads();
  }
}

// ---------------- xg GEMM: C[N][1024] = A[N][512] @ W[1024][512]^T + bias --
__global__ __launch_bounds__(256)
void xg_gemm(const float* __restrict__ A, const float* __restrict__ W,
             const float* __restrict__ b1, const float* __restrict__ b2,
             float* __restrict__ C)
{
  __shared__ float As[16][64], Ws[16][64];
  const int t  = threadIdx.x;
  const int n0 = blockIdx.x * 64, m0 = blockIdx.y * 64;
  const int ln = t >> 2, kq = t & 3;
  const int tx = t & 15, ty = t >> 4;
  float acc[4][4] = {};
  for (int k0 = 0; k0 < 512; k0 += 16) {
    const float4 a4 = *(const float4*)&A[(long)(n0 + ln) * 512 + k0 + kq * 4];
    const float4 w4 = *(const float4*)&W[(long)(m0 + ln) * 512 + k0 + kq * 4];
    __syncthreads();
    As[kq*4+0][ln] = a4.x; As[kq*4+1][ln] = a4.y;
    As[kq*4+2][ln] = a4.z; As[kq*4+3][ln] = a4.w;
    Ws[kq*4+0][ln] = w4.x; Ws[kq*4+1][ln] = w4.y;
    Ws[kq*4+2][ln] = w4.z; Ws[kq*4+3][ln] = w4.w;
    __syncthreads();
    #pragma unroll
    for (int k = 0; k < 16; ++k) {
      const float4 av = *(const float4*)&As[k][ty * 4];
      const float4 wv = *(const float4*)&Ws[k][tx * 4];
      acc[0][0] = fmaf(av.x, wv.x, acc[0][0]); acc[0][1] = fmaf(av.x, wv.y, acc[0][1]);
      acc[0][2] = fmaf(av.x, wv.z, acc[0][2]); acc[0][3] = fmaf(av.x, wv.w, acc[0][3]);
      acc[1][0] = fmaf(av.y, wv.x, acc[1][0]); acc[1][1] = fmaf(av.y, wv.y, acc[1][1]);
      acc[1][2] = fmaf(av.y, wv.z, acc[1][2]); acc[1][3] = fmaf(av.y, wv.w, acc[1][3]);
      acc[2][0] = fmaf(av.z, wv.x, acc[2][0]); acc[2][1] = fmaf(av.z, wv.y, acc[2][1]);
      acc[2][2] = fmaf(av.z, wv.z, acc[2][2]); acc[2][3] = fmaf(av.z, wv.w, acc[2][3]);
      acc[3][0] = fmaf(av.w, wv.x, acc[3][0]); acc[3][1] = fmaf(av.w, wv.y, acc[3][1]);
      acc[3][2] = fmaf(av.w, wv.z, acc[3][2]); acc[3][3] = fmaf(av.w, wv.w, acc[3][3]);
    }
  }
  const float4 bv1 = *(const float4*)&b1[m0 + tx * 4];
  const float4 bv2 = *(const float4*)&b2[m0 + tx * 4];
  #pragma unroll
  for (int i = 0; i < 4; ++i) {
    float4 o;
    o.x = acc[i][0] + bv1.x + bv2.x;
    o.y = acc[i][1] + bv1.y + bv2.y;
    o.z = acc[i][2] + bv1.z + bv2.z;
    o.w = acc[i][3] + bv1.w + bv2.w;
    *(float4*)&C[(long)(n0 + ty * 4 + i) * 1024 + m0 + tx * 4] = o;
  }
}

__global__ void fc_kernel(const float* __restrict__ hfinal,
                          const float* __restrict__ fc_w,
                          const float* __restrict__ fc_b,
                          float* __restrict__ out)
{
  const int tid = threadIdx.x;   // 512 threads: b = tid/4, quarter = tid%4
  const int b = tid >> 2, q = tid & 3;
  float s = 0.f;
  const float* hp = hfinal + b * 512 + q * 128;
  const float* wp = fc_w + q * 128;
  #pragma unroll 4
  for (int k = 0; k < 128; ++k) s += hp[k] * wp[k];
  s += __shfl_xor(s, 1, 64);
  s += __shfl_xor(s, 2, 64);
  if (q == 0) out[b] = s + fc_b[0];
}

extern "C" void kernel_launch(void* const* d_in, const int* in_sizes, int n_in,
                              void* d_out, int out_size, void* d_ws, size_t ws_size,
                              hipStream_t stream)
{
  const float* x     = (const float*)d_in[0];
  const float* wih0f = (const float*)d_in[1];
  const float* whh0f = (const float*)d_in[2];
  const float* bih0f = (const float*)d_in[3];
  const float* bhh0f = (const float*)d_in[4];
  const float* wih0b = (const float*)d_in[5];
  const float* whh0b = (const float*)d_in[6];
  const float* bih0b = (const float*)d_in[7];
  const float* bhh0b = (const float*)d_in[8];
  const float* wih1f = (const float*)d_in[9];
  const float* whh1f = (const float*)d_in[10];
  const float* bih1f = (const float*)d_in[11];
  const float* bhh1f = (const float*)d_in[12];
  const float* wih1b = (const float*)d_in[13];
  const float* whh1b = (const float*)d_in[14];
  const float* bih1b = (const float*)d_in[15];
  const float* bhh1b = (const float*)d_in[16];
  const float* fcw   = (const float*)d_in[17];
  const float* fcb   = (const float*)d_in[18];

  const size_t n_out0 = (size_t)T_ * B_ * 512;
  const size_t n_xg1b = (size_t)B_ * 1024;
  const size_t n_hst  = (size_t)B_ * 256;
  const size_t n_hfin = (size_t)B_ * 512;

  int CH = 0;
  const int cands[4] = {64, 32, 16, 8};
  for (int i = 0; i < 4; ++i) {
    const size_t need = (n_out0 + (size_t)cands[i] * B_ * 1024 + n_xg1b
                         + 2 * n_hst + n_hfin) * sizeof(float);
    if (need <= ws_size) { CH = cands[i]; break; }
  }
  if (!CH) return;

  float* out0   = (float*)d_ws;
  float* xgbuf  = out0 + n_out0;
  float* xg1b   = xgbuf + (size_t)CH * B_ * 1024;
  float* hstate = xg1b + n_xg1b;
  float* cstate = hstate + n_hst;
  float* hfinal = cstate + n_hst;

  // Layer 0: 128 independent 1024-thread WGs (2 dirs x 64 batch groups).
  l0_recur<<<dim3(2 * NG), dim3(RTH), 0, stream>>>(
      x, wih0f, whh0f, bih0f, bhh0f, wih0b, whh0b, bih0b, bhh0b, out0);

  // Layer 1 backward needs only t=T-1: one xg row-block + one step.
  xg_gemm<<<dim3(B_ / 64, 16), dim3(256), 0, stream>>>(
      out0 + (size_t)(T_ - 1) * B_ * 512, wih1b, bih1b, bhh1b, xg1b);
  l1_recur<<<dim3(NG), dim3(RTH), 0, stream>>>(
      whh1b, xg1b, hstate, cstate, hfinal + 256, 1, 1, 0, 1);

  // Layer 1 forward: time-chunked xg GEMM + sync-free recurrence.
  const int nch = T_ / CH;
  for (int c = 0; c < nch; ++c) {
    xg_gemm<<<dim3(CH * B_ / 64, 16), dim3(256), 0, stream>>>(
        out0 + (size_t)c * CH * B_ * 512, wih1f, bih1f, bhh1f, xgbuf);
    l1_recur<<<dim3(NG), dim3(RTH), 0, stream>>>(
        whh1f, xgbuf, hstate, cstate, hfinal, CH,
        c == 0 ? 1 : 0, 1, c == nch - 1 ? 1 : 0);
  }

  fc_kernel<<<dim3(1), dim3(512), 0, stream>>>(hfinal, fcw, fcb, (float*)d_out);
}

// Round 8
// 5301.396 us; speedup vs baseline: 5.4474x; 5.4474x over previous
//
#include <hip/hip_runtime.h>

// 2-layer biLSTM, B=128 T=256 IN=64 H=256, + fc to [128,1].
// Recurrence: 4-WG j-split groups (1 WG/CU, weights VGPR-resident under the
// 512-reg/SIMD wall). Per step: MAC over own k-slice -> 2-shuffle reduce ->
// acts -> publish own h-slice as tagged 8B pairs (RELAXED agent atomics,
// MALL-coherent) -> poll 3 peers' slices. One __syncthreads per step.
// L1 x-GEMM hoisted (chunked fp32 128x128 tile GEMM); L0 x inline (K=64).

typedef unsigned long long ull;

constexpr int B_ = 128, T_ = 256, IN_ = 64, H_ = 256;
constexpr int JW = 64;                    // hidden dims per WG (4-way split)

#define KEEP_REG(x) asm volatile("" : "+v"(x))

__device__ __forceinline__ float sigmoid_(float x) { return 1.f / (1.f + __expf(-x)); }
__device__ __forceinline__ float tanh_(float x)    { return 1.f - 2.f / (1.f + __expf(2.f * x)); }
// LDS h layout: 4 chunks of 64 padded to 68 (banks ks*68%32 = {0,4,8,12} -> conflict-free)
__device__ __forceinline__ int hidx(int k) { return (k >> 6) * 68 + (k & 63); }

// BB: batch rows per group. L0M: inline-x mode (layer 0).
template<int BB, bool L0M>
__global__ __launch_bounds__(256, 1)
void recur(const float* __restrict__ whh_f, const float* __restrict__ whh_b,
           const float* __restrict__ wih_f, const float* __restrict__ wih_b,
           const float* __restrict__ bih_f, const float* __restrict__ bhh_f,
           const float* __restrict__ bih_b, const float* __restrict__ bhh_b,
           const float* __restrict__ x,     // L0: [B][T][64]
           const float* __restrict__ xg,    // L1: chunk [ns][B][1024], biases folded
           float* __restrict__ out0,        // L0: [T][B][512]
           float* __restrict__ hstate, float* __restrict__ cstate,  // [B][256] (L1)
           float* __restrict__ hfinal,      // [B][512] (L1)
           ull* __restrict__ ring,          // [gidx][2 slots][BB*256] pairs
           int ngroup, int dir_base, int nsteps, int step_base,
           int first, int save, int lastW)
{
  const int bid = blockIdx.x;
  const int kw  = bid & 3;                  // j-split index
  const int gr  = (bid >> 2) % ngroup;      // batch group
  const int dl  = (bid >> 2) / ngroup;      // local dir
  const int d   = dir_base + dl;
  const int tid = threadIdx.x;
  const int jl  = tid >> 2;                 // 0..63
  const int ks  = tid & 3;                  // k-slice lane
  const int j   = kw * JW + jl;             // global hidden index
  const int bbase = gr * BB;
  const int gidx  = dl * ngroup + gr;

  const float* whh = d ? whh_b : whh_f;

  // ---- pinned weights: W_hh rows (g*256+j), k in [ks*64, ks*64+64) ----
  float wr[4][64];
  #pragma unroll
  for (int g = 0; g < 4; ++g) {
    const float* wrow = whh + (long)(g * H_ + j) * H_ + ks * 64;
    #pragma unroll
    for (int q = 0; q < 16; ++q) {
      const float4 w4 = *(const float4*)(wrow + q * 4);
      wr[g][q*4+0] = w4.x; wr[g][q*4+1] = w4.y;
      wr[g][q*4+2] = w4.z; wr[g][q*4+3] = w4.w;
    }
  }
  #pragma unroll
  for (int g = 0; g < 4; ++g)
    #pragma unroll
    for (int q = 0; q < 64; ++q) KEEP_REG(wr[g][q]);

  float wx[4][16], br[4];
  if constexpr (L0M) {
    const float* wih = d ? wih_b : wih_f;
    const float* bih = d ? bih_b : bih_f;
    const float* bhh = d ? bhh_b : bhh_f;
    #pragma unroll
    for (int g = 0; g < 4; ++g) {
      const float* xrow = wih + (long)(g * H_ + j) * IN_ + ks * 16;
      #pragma unroll
      for (int q = 0; q < 4; ++q) {
        const float4 w4 = *(const float4*)(xrow + q * 4);
        wx[g][q*4+0] = w4.x; wx[g][q*4+1] = w4.y;
        wx[g][q*4+2] = w4.z; wx[g][q*4+3] = w4.w;
      }
      br[g] = bih[g * H_ + j] + bhh[g * H_ + j];
      #pragma unroll
      for (int q = 0; q < 16; ++q) KEEP_REG(wx[g][q]);
    }
  }

  __shared__ alignas(16) float hbuf[2][BB][272];  // 4x68 padded chunks
  __shared__ alignas(16) float xt[2][4][64];      // L0 x tiles

  // h(-1) or chunk-restore into hbuf[0]
  for (int idx = tid; idx < BB * H_; idx += 256) {
    const int b = idx >> 8, k = idx & 255;
    hbuf[0][b][hidx(k)] = first ? 0.f
                                : hstate[(long)(bbase + b) * H_ + k];
  }
  float cs[BB];
  #pragma unroll
  for (int b = 0; b < BB; ++b)
    cs[b] = first ? 0.f : cstate[(long)(bbase + b) * H_ + j];

  if constexpr (L0M) {
    const int b = tid >> 6, kx = tid & 63;
    const int t0 = d ? T_ - 1 : 0;
    xt[0][b][kx] = x[((long)(bbase + b) * T_ + t0) * IN_ + kx];
  }

  float xr[BB][4], xn[BB][4];
  if constexpr (!L0M) {
    #pragma unroll
    for (int b = 0; b < BB; ++b)
      #pragma unroll
      for (int g = 0; g < 4; ++g)
        xr[b][g] = xg[(long)(bbase + b) * 1024 + g * H_ + j];
  }
  __syncthreads();

  const long ringstride = (long)2 * BB * H_;   // per gidx

  for (int s = 0; s < nsteps; ++s) {
    const int p = s & 1, wp = p ^ 1;
    const int gstep = step_base + s;

    // A) issue prefetches (reg-only; LDS writes deferred past the barrier)
    float xpre = 0.f;
    if constexpr (L0M) {
      if (s + 1 < nsteps) {
        const int b = tid >> 6, kx = tid & 63;
        const int ttn = d ? (T_ - 2 - s) : (s + 1);
        xpre = x[((long)(bbase + b) * T_ + ttn) * IN_ + kx];
      }
    } else {
      const int sn = (s + 1 < nsteps) ? s + 1 : s;
      #pragma unroll
      for (int b = 0; b < BB; ++b)
        #pragma unroll
        for (int g = 0; g < 4; ++g)
          xn[b][g] = xg[((long)sn * B_ + bbase + b) * 1024 + g * H_ + j];
    }

    // B) poll peers' h(t-1) slices into hbuf[p]
    if (s > 0) {
      const unsigned want = (unsigned)gstep;
      const int slot = (gstep - 1) & 1;
      ull* rg = ring + gidx * ringstride + (long)slot * (BB * H_);
      constexpr int NP = 3 * JW * BB;
      constexpr int NL = (NP + 255) / 256;
      ull  vv[NL];
      int  bb_[NL], jp_[NL], on_[NL];
      #pragma unroll
      for (int q = 0; q < NL; ++q) {
        const int pidx = tid + q * 256;
        on_[q] = pidx < NP;
        if (on_[q]) {
          const int psl = pidx / (JW * BB);
          const int rem = pidx % (JW * BB);
          bb_[q] = rem >> 6;
          const int kwp = psl + (psl >= kw ? 1 : 0);
          jp_[q] = kwp * JW + (rem & 63);
          vv[q] = __hip_atomic_load(rg + bb_[q] * H_ + jp_[q],
                                    __ATOMIC_RELAXED, __HIP_MEMORY_SCOPE_AGENT);
        }
      }
      long gd = 0;
      for (;;) {
        bool ok = true;
        #pragma unroll
        for (int q = 0; q < NL; ++q)
          if (on_[q] && (unsigned)(vv[q] >> 32) != want) ok = false;
        if (ok) break;
        if (++gd > (1L << 20)) break;   // bail instead of hanging
        __builtin_amdgcn_s_sleep(1);
        #pragma unroll
        for (int q = 0; q < NL; ++q)
          if (on_[q] && (unsigned)(vv[q] >> 32) != want)
            vv[q] = __hip_atomic_load(rg + bb_[q] * H_ + jp_[q],
                                      __ATOMIC_RELAXED, __HIP_MEMORY_SCOPE_AGENT);
      }
      #pragma unroll
      for (int q = 0; q < NL; ++q)
        if (on_[q]) hbuf[p][bb_[q]][hidx(jp_[q])] = __uint_as_float((unsigned)vv[q]);
    }
    __syncthreads();   // C) hbuf[p] complete (and prev-step LDS reads done)

    // D) MAC over own k-slice
    float acc[BB][4];
    #pragma unroll
    for (int b = 0; b < BB; ++b)
      #pragma unroll
      for (int g = 0; g < 4; ++g) acc[b][g] = 0.f;
    #pragma unroll
    for (int b = 0; b < BB; ++b) {
      const float* hb = &hbuf[p][b][ks * 68];
      #pragma unroll
      for (int q = 0; q < 16; ++q) {
        const float4 hv = *(const float4*)(hb + q * 4);
        #pragma unroll
        for (int g = 0; g < 4; ++g) {
          acc[b][g] = fmaf(hv.x, wr[g][q*4+0], acc[b][g]);
          acc[b][g] = fmaf(hv.y, wr[g][q*4+1], acc[b][g]);
          acc[b][g] = fmaf(hv.z, wr[g][q*4+2], acc[b][g]);
          acc[b][g] = fmaf(hv.w, wr[g][q*4+3], acc[b][g]);
        }
      }
      if constexpr (L0M) {
        const float* xb = &xt[p][b][ks * 16];
        #pragma unroll
        for (int q = 0; q < 4; ++q) {
          const float4 xv = *(const float4*)(xb + q * 4);
          #pragma unroll
          for (int g = 0; g < 4; ++g) {
            acc[b][g] = fmaf(xv.x, wx[g][q*4+0], acc[b][g]);
            acc[b][g] = fmaf(xv.y, wx[g][q*4+1], acc[b][g]);
            acc[b][g] = fmaf(xv.z, wx[g][q*4+2], acc[b][g]);
            acc[b][g] = fmaf(xv.w, wx[g][q*4+3], acc[b][g]);
          }
        }
      }
    }

    // E) 4-lane allreduce + activations (replicated across the quad)
    float hv_[BB];
    #pragma unroll
    for (int b = 0; b < BB; ++b) {
      #pragma unroll
      for (int g = 0; g < 4; ++g) {
        float a = acc[b][g];
        a += __shfl_xor(a, 1, 64);
        a += __shfl_xor(a, 2, 64);
        if constexpr (L0M) acc[b][g] = a + br[g];
        else               acc[b][g] = a + xr[b][g];
      }
      const float ig = sigmoid_(acc[b][0]);
      const float fg = sigmoid_(acc[b][1]);
      const float gg = tanh_(acc[b][2]);
      const float og = sigmoid_(acc[b][3]);
      cs[b] = fg * cs[b] + ig * gg;
      hv_[b] = og * tanh_(cs[b]);
    }

    // F) publish + local/global stores (lane ks handles batch row b=ks)
    if (ks < BB) {
      float hmine = hv_[0], cmine = cs[0];
      #pragma unroll
      for (int b = 1; b < BB; ++b)
        if (ks == b) { hmine = hv_[b]; cmine = cs[b]; }

      if (s < nsteps - 1) {
        const ull pv = ((ull)(unsigned)(gstep + 1) << 32) | (unsigned)__float_as_uint(hmine);
        __hip_atomic_store(ring + gidx * ringstride + (long)(gstep & 1) * (BB * H_)
                               + ks * H_ + j,
                           pv, __ATOMIC_RELAXED, __HIP_MEMORY_SCOPE_AGENT);
      }
      hbuf[wp][ks][hidx(j)] = hmine;

      if constexpr (L0M) {
        const int tt = d ? (T_ - 1 - s) : s;
        out0[((long)tt * B_ + bbase + ks) * 512 + d * H_ + j] = hmine;
      } else {
        if (s == nsteps - 1) {
          if (lastW)
            hfinal[(long)(bbase + ks) * 512 + (d ? H_ : 0) + j] = hmine;
          if (save) {
            hstate[(long)(bbase + ks) * H_ + j] = hmine;
            cstate[(long)(bbase + ks) * H_ + j] = cmine;
          }
        }
      }
    }

    // deferred LDS writes of prefetched data (consumed after next barrier)
    if constexpr (L0M) {
      if (s + 1 < nsteps) {
        const int b = tid >> 6, kx = tid & 63;
        xt[wp][b][kx] = xpre;
      }
    } else {
      #pragma unroll
      for (int b = 0; b < BB; ++b)
        #pragma unroll
        for (int g = 0; g < 4; ++g) xr[b][g] = xn[b][g];
    }
  }
}

// C[M][1024] = A[M][512] @ W[1024][512]^T + b1 + b2.  M = gridDim.x*128.
__global__ __launch_bounds__(256, 2)
void xg_gemm(const float* __restrict__ A, const float* __restrict__ W,
             const float* __restrict__ b1, const float* __restrict__ b2,
             float* __restrict__ C)
{
  __shared__ float As[16][128];
  __shared__ float Bs[16][132];
  const int tid = threadIdx.x;
  const int tx = tid & 15, ty = tid >> 4;
  const long m0 = (long)blockIdx.x * 128;
  const int  n0 = blockIdx.y * 128;
  const int sr = tid >> 1;
  const int sk = (tid & 1) * 8;
  const float* Ar = A + (m0 + sr) * 512 + sk;
  const float* Wr = W + (long)(n0 + sr) * 512 + sk;
  float acc[8][8];
  #pragma unroll
  for (int i = 0; i < 8; ++i)
    #pragma unroll
    for (int jj = 0; jj < 8; ++jj) acc[i][jj] = 0.f;

  for (int k0 = 0; k0 < 512; k0 += 16) {
    const float4 a0 = *(const float4*)(Ar + k0);
    const float4 a1 = *(const float4*)(Ar + k0 + 4);
    const float4 w0 = *(const float4*)(Wr + k0);
    const float4 w1 = *(const float4*)(Wr + k0 + 4);
    __syncthreads();
    As[sk+0][sr]=a0.x; As[sk+1][sr]=a0.y; As[sk+2][sr]=a0.z; As[sk+3][sr]=a0.w;
    As[sk+4][sr]=a1.x; As[sk+5][sr]=a1.y; As[sk+6][sr]=a1.z; As[sk+7][sr]=a1.w;
    Bs[sk+0][sr]=w0.x; Bs[sk+1][sr]=w0.y; Bs[sk+2][sr]=w0.z; Bs[sk+3][sr]=w0.w;
    Bs[sk+4][sr]=w1.x; Bs[sk+5][sr]=w1.y; Bs[sk+6][sr]=w1.z; Bs[sk+7][sr]=w1.w;
    __syncthreads();
    #pragma unroll
    for (int k = 0; k < 16; ++k) {
      const float4 av0 = *(const float4*)&As[k][ty * 8];
      const float4 av1 = *(const float4*)&As[k][ty * 8 + 4];
      const float4 bv0 = *(const float4*)&Bs[k][tx * 8];
      const float4 bv1 = *(const float4*)&Bs[k][tx * 8 + 4];
      const float a_[8] = {av0.x,av0.y,av0.z,av0.w,av1.x,av1.y,av1.z,av1.w};
      const float b_[8] = {bv0.x,bv0.y,bv0.z,bv0.w,bv1.x,bv1.y,bv1.z,bv1.w};
      #pragma unroll
      for (int i = 0; i < 8; ++i)
        #pragma unroll
        for (int jj = 0; jj < 8; ++jj)
          acc[i][jj] = fmaf(a_[i], b_[jj], acc[i][jj]);
    }
  }
  float bsum[8];
  #pragma unroll
  for (int jj = 0; jj < 8; ++jj) {
    const int col = n0 + tx * 8 + jj;
    bsum[jj] = b1[col] + b2[col];
  }
  #pragma unroll
  for (int i = 0; i < 8; ++i) {
    const long crow = m0 + ty * 8 + i;
    #pragma unroll
    for (int q = 0; q < 2; ++q) {
      float4 o;
      o.x = acc[i][q*4+0] + bsum[q*4+0];
      o.y = acc[i][q*4+1] + bsum[q*4+1];
      o.z = acc[i][q*4+2] + bsum[q*4+2];
      o.w = acc[i][q*4+3] + bsum[q*4+3];
      *(float4*)&C[crow * 1024 + n0 + tx * 8 + q * 4] = o;
    }
  }
}

__global__ void fc_kernel(const float* __restrict__ hfinal,
                          const float* __restrict__ fc_w,
                          const float* __restrict__ fc_b,
                          float* __restrict__ out)
{
  const int tid = threadIdx.x;   // 512 threads: b = tid/4, quarter = tid%4
  const int b = tid >> 2, q = tid & 3;
  float s = 0.f;
  const float* hp = hfinal + b * 512 + q * 128;
  const float* wp = fc_w + q * 128;
  #pragma unroll 4
  for (int k = 0; k < 128; ++k) s += hp[k] * wp[k];
  s += __shfl_xor(s, 1, 64);
  s += __shfl_xor(s, 2, 64);
  if (q == 0) out[b] = s + fc_b[0];
}

extern "C" void kernel_launch(void* const* d_in, const int* in_sizes, int n_in,
                              void* d_out, int out_size, void* d_ws, size_t ws_size,
                              hipStream_t stream)
{
  const float* x     = (const float*)d_in[0];
  const float* wih0f = (const float*)d_in[1];
  const float* whh0f = (const float*)d_in[2];
  const float* bih0f = (const float*)d_in[3];
  const float* bhh0f = (const float*)d_in[4];
  const float* wih0b = (const float*)d_in[5];
  const float* whh0b = (const float*)d_in[6];
  const float* bih0b = (const float*)d_in[7];
  const float* bhh0b = (const float*)d_in[8];
  const float* wih1f = (const float*)d_in[9];
  const float* whh1f = (const float*)d_in[10];
  const float* bih1f = (const float*)d_in[11];
  const float* bhh1f = (const float*)d_in[12];
  const float* wih1b = (const float*)d_in[13];
  const float* whh1b = (const float*)d_in[14];
  const float* bih1b = (const float*)d_in[15];
  const float* bhh1b = (const float*)d_in[16];
  const float* fcw   = (const float*)d_in[17];
  const float* fcb   = (const float*)d_in[18];

  const size_t n_out0 = (size_t)T_ * B_ * 512;
  const size_t nring0 = 64ull * 2 * 4 * 256;   // [64 gidx][2 slots][BB=4 * 256]
  const size_t nring1 = 64ull * 2 * 2 * 256;   // [64 gidx][2 slots][BB=2 * 256]

  int CH = 0;
  const int cands[4] = {64, 32, 16, 8};
  const size_t fixedf = n_out0 + (size_t)B_ * 1024 + 2 * (size_t)B_ * 256
                      + (size_t)B_ * 512;
  for (int i = 0; i < 4; ++i) {
    const size_t need = 4 * (fixedf + (size_t)cands[i] * B_ * 1024)
                      + 8 * (nring0 + nring1);
    if (need <= ws_size) { CH = cands[i]; break; }
  }
  if (!CH) return;

  float* out0 = (float*)d_ws;
  float* xg1  = out0 + n_out0;                      // [CH][B][1024]
  float* xg1b = xg1 + (size_t)CH * B_ * 1024;       // [1][B][1024]
  float* hst1 = xg1b + (size_t)B_ * 1024;
  float* cst1 = hst1 + (size_t)B_ * 256;
  float* hfin = cst1 + (size_t)B_ * 256;            // [B][512]
  ull*  ring0 = (ull*)(hfin + (size_t)B_ * 512);
  ull*  ring1 = ring0 + nring0;

  hipMemsetAsync(ring0, 0, (nring0 + nring1) * sizeof(ull), stream);

  // Layer 0: 2 dirs x 32 groups (BB=4) x 4 j-split WGs = 256 WGs, 1/CU.
  recur<4, true><<<dim3(256), dim3(256), 0, stream>>>(
      whh0f, whh0b, wih0f, wih0b, bih0f, bhh0f, bih0b, bhh0b,
      x, nullptr, out0, nullptr, nullptr, nullptr, ring0,
      /*ngroup*/32, /*dir_base*/0, /*nsteps*/T_, /*step_base*/0,
      /*first*/1, /*save*/0, /*lastW*/0);

  // Layer 1 backward: only t=T-1 needed -> one xg row-block + one step.
  xg_gemm<<<dim3(1, 8), dim3(256), 0, stream>>>(
      out0 + (size_t)(T_ - 1) * B_ * 512, wih1b, bih1b, bhh1b, xg1b);
  recur<2, false><<<dim3(256), dim3(256), 0, stream>>>(
      whh1f, whh1b, nullptr, nullptr, nullptr, nullptr, nullptr, nullptr,
      nullptr, xg1b, nullptr, hst1, cst1, hfin, ring1,
      /*ngroup*/64, /*dir_base*/1, /*nsteps*/1, /*step_base*/0,
      /*first*/1, /*save*/0, /*lastW*/1);

  // Layer 1 forward: chunked xg GEMM + recurrence (64 groups BB=2 x 4 = 256 WGs).
  const int nch = T_ / CH;
  for (int c = 0; c < nch; ++c) {
    xg_gemm<<<dim3(CH, 8), dim3(256), 0, stream>>>(
        out0 + (size_t)c * CH * B_ * 512, wih1f, bih1f, bhh1f, xg1);
    recur<2, false><<<dim3(256), dim3(256), 0, stream>>>(
        whh1f, whh1b, nullptr, nullptr, nullptr, nullptr, nullptr, nullptr,
        nullptr, xg1, nullptr, hst1, cst1, hfin, ring1,
        /*ngroup*/64, /*dir_base*/0, /*nsteps*/CH, /*step_base*/c * CH,
        /*first*/c == 0 ? 1 : 0, /*save*/1, /*lastW*/c == nch - 1 ? 1 : 0);
  }

  fc_kernel<<<dim3(1), dim3(512), 0, stream>>>(hfin, fcw, fcb, (float*)d_out);
}

// Round 10
// 2500.396 us; speedup vs baseline: 11.5497x; 2.1202x over previous
//
#include <hip/hip_runtime.h>

// 2-layer biLSTM, B=128 T=256 IN=64 H=256, + fc to [128,1].
// Topology (R8, proven): group = (dir, batch-block), 4 WGs x 256 thr,
// thread = (jl 0..63, ks 0..3); per step MAC own k-slice -> 2-shuffle quad
// allreduce -> acts -> publish own h-slice as tagged 8B pairs (RELAXED agent
// atomics) -> poll 3 peers. One __syncthreads per step.
// R9 weight residency (fits the 256-arch-VGPR wall):
//   W_hh gates i,f -> 128 VGPRs (pinned);  W_hh gates g,o -> 136KB LDS;
//   L0 W_ih -> streamed from L2 each step (coalesced, pre-poll).
// R10 FIX: xt[wp] deferred write moved BEFORE the barrier (R9 had a
// cross-thread LDS race: pre-barrier x-MAC read vs loop-end write).

typedef unsigned long long ull;

constexpr int B_ = 128, T_ = 256, IN_ = 64, H_ = 256;
constexpr int JW = 64;                    // hidden dims per WG (4-way j split)

#define KEEP_REG(x) asm volatile("" : "+v"(x))

__device__ __forceinline__ float sigmoid_(float x) { return 1.f / (1.f + __expf(-x)); }
__device__ __forceinline__ float tanh_(float x)    { return 1.f - 2.f / (1.f + __expf(2.f * x)); }
// hbuf row layout: 4 chunks of 64 padded to 68 (ks*68%32 = ks*4 banks -> spread)
__device__ __forceinline__ int hidx(int k) { return (k >> 6) * 68 + (k & 63); }
// LDS weight layout: ((gp*64+jl)*4+ks)*68 + k'
__device__ __forceinline__ int widx(int gp, int jl, int ks, int kp) {
  return ((gp * 64 + jl) * 4 + ks) * 68 + kp;
}

// BB: batch rows per group. L0M: layer-0 mode (inline x via streamed W_ih).
template<int BB, bool L0M>
__global__ __launch_bounds__(256, 1)
void recur(const float* __restrict__ whh_f, const float* __restrict__ whh_b,
           const float* __restrict__ wih_f, const float* __restrict__ wih_b,
           const float* __restrict__ bih_f, const float* __restrict__ bhh_f,
           const float* __restrict__ bih_b, const float* __restrict__ bhh_b,
           const float* __restrict__ x,     // L0: [B][T][64]
           const float* __restrict__ xg,    // L1: [ns][B][1024], biases folded
           float* __restrict__ out0,        // L0: [T][B][512]
           float* __restrict__ hstate, float* __restrict__ cstate,  // [B][256]
           float* __restrict__ hfinal,      // [B][512] (L1)
           ull* __restrict__ ring,          // [gidx][2 slots][BB*256] pairs
           int ngroup, int dir_base, int nsteps, int step_base,
           int first, int save, int lastW)
{
  const int bid = blockIdx.x;
  const int kw  = bid & 3;
  const int gr  = (bid >> 2) % ngroup;
  const int dl  = (bid >> 2) / ngroup;
  const int d   = dir_base + dl;
  const int tid = threadIdx.x;
  const int jl  = tid >> 2;                 // 0..63
  const int ks  = tid & 3;                  // k-slice lane
  const int j   = kw * JW + jl;             // global hidden index
  const int bbase = gr * BB;
  const int gidx  = dl * ngroup + gr;

  const float* whh  = d ? whh_b : whh_f;
  const float* wihp = d ? wih_b : wih_f;

  // ---- VGPR gates i(0), f(1): 128 pinned floats ----
  float wr[2][64];
  #pragma unroll
  for (int g = 0; g < 2; ++g) {
    const float* wrow = whh + (long)(g * H_ + j) * H_ + ks * 64;
    #pragma unroll
    for (int q = 0; q < 16; ++q) {
      const float4 w4 = *(const float4*)(wrow + q * 4);
      wr[g][q*4+0] = w4.x; wr[g][q*4+1] = w4.y;
      wr[g][q*4+2] = w4.z; wr[g][q*4+3] = w4.w;
    }
  }
  #pragma unroll
  for (int g = 0; g < 2; ++g)
    #pragma unroll
    for (int q = 0; q < 64; ++q) KEEP_REG(wr[g][q]);

  // ---- LDS gates g(2), o(3): staged once ----
  __shared__ alignas(16) float wlds[2 * 64 * 4 * 68];   // 139264 B
  __shared__ alignas(16) float hbuf[2][BB][272];
  __shared__ alignas(16) float xt[2][4][64];            // L0 x tiles
  #pragma unroll
  for (int gp = 0; gp < 2; ++gp) {
    const float* wrow = whh + (long)((gp + 2) * H_ + j) * H_ + ks * 64;
    float* dst = &wlds[widx(gp, jl, ks, 0)];
    #pragma unroll
    for (int q = 0; q < 16; ++q)
      *(float4*)(dst + q * 4) = *(const float4*)(wrow + q * 4);
  }

  float br[4];
  if constexpr (L0M) {
    const float* bih = d ? bih_b : bih_f;
    const float* bhh = d ? bhh_b : bhh_f;
    #pragma unroll
    for (int g = 0; g < 4; ++g) br[g] = bih[g * H_ + j] + bhh[g * H_ + j];
  }

  // h(-1) / chunk restore
  for (int idx = tid; idx < BB * H_; idx += 256) {
    const int b = idx >> 8, k = idx & 255;
    hbuf[0][b][hidx(k)] = first ? 0.f : hstate[(long)(bbase + b) * H_ + k];
  }
  float cs[BB];
  #pragma unroll
  for (int b = 0; b < BB; ++b)
    cs[b] = first ? 0.f : cstate[(long)(bbase + b) * H_ + j];

  if constexpr (L0M) {
    const int b = tid >> 6, kx = tid & 63;
    const int t0 = d ? T_ - 1 : 0;
    xt[0][b][kx] = x[((long)(bbase + b) * T_ + t0) * IN_ + kx];
  }
  float xr[BB][4], xn[BB][4];
  if constexpr (!L0M) {
    #pragma unroll
    for (int b = 0; b < BB; ++b)
      #pragma unroll
      for (int g = 0; g < 4; ++g)
        xr[b][g] = xg[(long)(bbase + b) * 1024 + g * H_ + j];
  }
  __syncthreads();

  const long ringstride = (long)2 * BB * H_;

  for (int s = 0; s < nsteps; ++s) {
    const int p = s & 1, wp = p ^ 1;
    const int gstep = step_base + s;

    // A) prefetches for next step (reg-only here)
    float xpre = 0.f;
    if constexpr (L0M) {
      if (s + 1 < nsteps) {
        const int b = tid >> 6, kx = tid & 63;
        const int ttn = d ? (T_ - 2 - s) : (s + 1);
        xpre = x[((long)(bbase + b) * T_ + ttn) * IN_ + kx];
      }
    } else {
      const int sn = (s + 1 < nsteps) ? s + 1 : s;
      #pragma unroll
      for (int b = 0; b < BB; ++b)
        #pragma unroll
        for (int g = 0; g < 4; ++g)
          xn[b][g] = xg[((long)sn * B_ + bbase + b) * 1024 + g * H_ + j];
    }

    float acc[BB][4];
    #pragma unroll
    for (int b = 0; b < BB; ++b)
      #pragma unroll
      for (int g = 0; g < 4; ++g) acc[b][g] = 0.f;

    // B) L0: ih contribution (L2-streamed weights, independent of h -> pre-poll)
    if constexpr (L0M) {
      #pragma unroll
      for (int gp = 0; gp < 2; ++gp) {
        const int g0 = 2 * gp, g1 = 2 * gp + 1;
        const float* wa = wihp + (long)(g0 * H_ + j) * IN_ + ks * 16;
        const float* wb = wihp + (long)(g1 * H_ + j) * IN_ + ks * 16;
        float4 wa_[4], wb_[4];
        #pragma unroll
        for (int q = 0; q < 4; ++q) { wa_[q] = *(const float4*)(wa + q * 4);
                                      wb_[q] = *(const float4*)(wb + q * 4); }
        #pragma unroll
        for (int b = 0; b < BB; ++b) {
          #pragma unroll
          for (int q = 0; q < 4; ++q) {
            const float4 xv = *(const float4*)&xt[p][b][ks * 16 + q * 4];
            acc[b][g0] = fmaf(xv.x, wa_[q].x, acc[b][g0]);
            acc[b][g0] = fmaf(xv.y, wa_[q].y, acc[b][g0]);
            acc[b][g0] = fmaf(xv.z, wa_[q].z, acc[b][g0]);
            acc[b][g0] = fmaf(xv.w, wa_[q].w, acc[b][g0]);
            acc[b][g1] = fmaf(xv.x, wb_[q].x, acc[b][g1]);
            acc[b][g1] = fmaf(xv.y, wb_[q].y, acc[b][g1]);
            acc[b][g1] = fmaf(xv.z, wb_[q].z, acc[b][g1]);
            acc[b][g1] = fmaf(xv.w, wb_[q].w, acc[b][g1]);
          }
        }
      }
      // B2) RACE FIX: write next step's x tile BEFORE the barrier, so the
      // barrier orders it against next iteration's pre-barrier x-MAC reads.
      if (s + 1 < nsteps) {
        const int b = tid >> 6, kx = tid & 63;
        xt[wp][b][kx] = xpre;
      }
    }

    // C) poll peers' h(t-1) into hbuf[p]
    if (s > 0) {
      const unsigned want = (unsigned)gstep;
      ull* rg = ring + gidx * ringstride + (long)((gstep - 1) & 1) * (BB * H_);
      constexpr int NP = 3 * JW * BB;
      constexpr int NL = (NP + 255) / 256;
      ull vv[NL];
      #pragma unroll
      for (int q = 0; q < NL; ++q) {
        const int pidx = tid + q * 256;
        if (pidx < NP) {
          const int psl = pidx / (JW * BB), rem = pidx % (JW * BB);
          const int kwp = psl + (psl >= kw ? 1 : 0);
          vv[q] = __hip_atomic_load(rg + (rem >> 6) * H_ + kwp * JW + (rem & 63),
                                    __ATOMIC_RELAXED, __HIP_MEMORY_SCOPE_AGENT);
        }
      }
      long gd = 0;
      for (;;) {
        bool ok = true;
        #pragma unroll
        for (int q = 0; q < NL; ++q)
          if (tid + q * 256 < NP && (unsigned)(vv[q] >> 32) != want) ok = false;
        if (ok) break;
        if (++gd > (1L << 20)) break;   // bail instead of hanging
        __builtin_amdgcn_s_sleep(1);
        #pragma unroll
        for (int q = 0; q < NL; ++q) {
          const int pidx = tid + q * 256;
          if (pidx < NP && (unsigned)(vv[q] >> 32) != want) {
            const int psl = pidx / (JW * BB), rem = pidx % (JW * BB);
            const int kwp = psl + (psl >= kw ? 1 : 0);
            vv[q] = __hip_atomic_load(rg + (rem >> 6) * H_ + kwp * JW + (rem & 63),
                                      __ATOMIC_RELAXED, __HIP_MEMORY_SCOPE_AGENT);
          }
        }
      }
      #pragma unroll
      for (int q = 0; q < NL; ++q) {
        const int pidx = tid + q * 256;
        if (pidx < NP) {
          const int psl = pidx / (JW * BB), rem = pidx % (JW * BB);
          const int kwp = psl + (psl >= kw ? 1 : 0);
          hbuf[p][rem >> 6][hidx(kwp * JW + (rem & 63))] =
              __uint_as_float((unsigned)vv[q]);
        }
      }
    }
    __syncthreads();   // hbuf[p] complete; orders B2 write vs next-iter B read

    // D) hh MAC: reg gates i,f + LDS gates g,o
    #pragma unroll
    for (int q = 0; q < 16; ++q) {
      const float4 wg = *(const float4*)&wlds[widx(0, jl, ks, q * 4)];
      const float4 wo = *(const float4*)&wlds[widx(1, jl, ks, q * 4)];
      #pragma unroll
      for (int b = 0; b < BB; ++b) {
        const float4 hv = *(const float4*)&hbuf[p][b][ks * 68 + q * 4];
        acc[b][0] = fmaf(hv.x, wr[0][q*4+0], acc[b][0]);
        acc[b][0] = fmaf(hv.y, wr[0][q*4+1], acc[b][0]);
        acc[b][0] = fmaf(hv.z, wr[0][q*4+2], acc[b][0]);
        acc[b][0] = fmaf(hv.w, wr[0][q*4+3], acc[b][0]);
        acc[b][1] = fmaf(hv.x, wr[1][q*4+0], acc[b][1]);
        acc[b][1] = fmaf(hv.y, wr[1][q*4+1], acc[b][1]);
        acc[b][1] = fmaf(hv.z, wr[1][q*4+2], acc[b][1]);
        acc[b][1] = fmaf(hv.w, wr[1][q*4+3], acc[b][1]);
        acc[b][2] = fmaf(hv.x, wg.x, acc[b][2]);
        acc[b][2] = fmaf(hv.y, wg.y, acc[b][2]);
        acc[b][2] = fmaf(hv.z, wg.z, acc[b][2]);
        acc[b][2] = fmaf(hv.w, wg.w, acc[b][2]);
        acc[b][3] = fmaf(hv.x, wo.x, acc[b][3]);
        acc[b][3] = fmaf(hv.y, wo.y, acc[b][3]);
        acc[b][3] = fmaf(hv.z, wo.z, acc[b][3]);
        acc[b][3] = fmaf(hv.w, wo.w, acc[b][3]);
      }
    }

    // E) quad allreduce + activations
    float hv_[BB];
    #pragma unroll
    for (int b = 0; b < BB; ++b) {
      #pragma unroll
      for (int g = 0; g < 4; ++g) {
        float a = acc[b][g];
        a += __shfl_xor(a, 1, 64);
        a += __shfl_xor(a, 2, 64);
        if constexpr (L0M) acc[b][g] = a + br[g];
        else               acc[b][g] = a + xr[b][g];
      }
      const float ig = sigmoid_(acc[b][0]);
      const float fg = sigmoid_(acc[b][1]);
      const float gg = tanh_(acc[b][2]);
      const float og = sigmoid_(acc[b][3]);
      cs[b] = fg * cs[b] + ig * gg;
      hv_[b] = og * tanh_(cs[b]);
    }

    // F) publish + stores (lane ks handles batch row b=ks)
    if (ks < BB) {
      float hmine = hv_[0], cmine = cs[0];
      #pragma unroll
      for (int b = 1; b < BB; ++b)
        if (ks == b) { hmine = hv_[b]; cmine = cs[b]; }

      if (s < nsteps - 1) {
        const ull pv = ((ull)(unsigned)(gstep + 1) << 32) | (unsigned)__float_as_uint(hmine);
        __hip_atomic_store(ring + gidx * ringstride + (long)(gstep & 1) * (BB * H_)
                               + ks * H_ + j,
                           pv, __ATOMIC_RELAXED, __HIP_MEMORY_SCOPE_AGENT);
      }
      hbuf[wp][ks][hidx(j)] = hmine;

      if constexpr (L0M) {
        const int tt = d ? (T_ - 1 - gstep) : gstep;
        out0[((long)tt * B_ + bbase + ks) * 512 + d * H_ + j] = hmine;
      } else {
        if (s == nsteps - 1 && lastW)
          hfinal[(long)(bbase + ks) * 512 + (d ? H_ : 0) + j] = hmine;
      }
      if (save && s == nsteps - 1) {
        hstate[(long)(bbase + ks) * H_ + j] = hmine;
        cstate[(long)(bbase + ks) * H_ + j] = cmine;
      }
    }

    // deferred reg update of prefetched xg (registers: no cross-thread hazard)
    if constexpr (!L0M) {
      #pragma unroll
      for (int b = 0; b < BB; ++b)
        #pragma unroll
        for (int g = 0; g < 4; ++g) xr[b][g] = xn[b][g];
    }
  }
}

// C[M][1024] = A[M][512] @ W[1024][512]^T + b1 + b2.
__global__ __launch_bounds__(256, 2)
void xg_gemm(const float* __restrict__ A, const float* __restrict__ W,
             const float* __restrict__ b1, const float* __restrict__ b2,
             float* __restrict__ C)
{
  __shared__ float As[16][128];
  __shared__ float Bs[16][132];
  const int tid = threadIdx.x;
  const int tx = tid & 15, ty = tid >> 4;
  const long m0 = (long)blockIdx.x * 128;
  const int  n0 = blockIdx.y * 128;
  const int sr = tid >> 1;
  const int sk = (tid & 1) * 8;
  const float* Ar = A + (m0 + sr) * 512 + sk;
  const float* Wr = W + (long)(n0 + sr) * 512 + sk;
  float acc[8][8];
  #pragma unroll
  for (int i = 0; i < 8; ++i)
    #pragma unroll
    for (int jj = 0; jj < 8; ++jj) acc[i][jj] = 0.f;

  for (int k0 = 0; k0 < 512; k0 += 16) {
    const float4 a0 = *(const float4*)(Ar + k0);
    const float4 a1 = *(const float4*)(Ar + k0 + 4);
    const float4 w0 = *(const float4*)(Wr + k0);
    const float4 w1 = *(const float4*)(Wr + k0 + 4);
    __syncthreads();
    As[sk+0][sr]=a0.x; As[sk+1][sr]=a0.y; As[sk+2][sr]=a0.z; As[sk+3][sr]=a0.w;
    As[sk+4][sr]=a1.x; As[sk+5][sr]=a1.y; As[sk+6][sr]=a1.z; As[sk+7][sr]=a1.w;
    Bs[sk+0][sr]=w0.x; Bs[sk+1][sr]=w0.y; Bs[sk+2][sr]=w0.z; Bs[sk+3][sr]=w0.w;
    Bs[sk+4][sr]=w1.x; Bs[sk+5][sr]=w1.y; Bs[sk+6][sr]=w1.z; Bs[sk+7][sr]=w1.w;
    __syncthreads();
    #pragma unroll
    for (int k = 0; k < 16; ++k) {
      const float4 av0 = *(const float4*)&As[k][ty * 8];
      const float4 av1 = *(const float4*)&As[k][ty * 8 + 4];
      const float4 bv0 = *(const float4*)&Bs[k][tx * 8];
      const float4 bv1 = *(const float4*)&Bs[k][tx * 8 + 4];
      const float a_[8] = {av0.x,av0.y,av0.z,av0.w,av1.x,av1.y,av1.z,av1.w};
      const float b_[8] = {bv0.x,bv0.y,bv0.z,bv0.w,bv1.x,bv1.y,bv1.z,bv1.w};
      #pragma unroll
      for (int i = 0; i < 8; ++i)
        #pragma unroll
        for (int jj = 0; jj < 8; ++jj)
          acc[i][jj] = fmaf(a_[i], b_[jj], acc[i][jj]);
    }
  }
  float bsum[8];
  #pragma unroll
  for (int jj = 0; jj < 8; ++jj) {
    const int col = n0 + tx * 8 + jj;
    bsum[jj] = b1[col] + b2[col];
  }
  #pragma unroll
  for (int i = 0; i < 8; ++i) {
    const long crow = m0 + ty * 8 + i;
    #pragma unroll
    for (int q = 0; q < 2; ++q) {
      float4 o;
      o.x = acc[i][q*4+0] + bsum[q*4+0];
      o.y = acc[i][q*4+1] + bsum[q*4+1];
      o.z = acc[i][q*4+2] + bsum[q*4+2];
      o.w = acc[i][q*4+3] + bsum[q*4+3];
      *(float4*)&C[crow * 1024 + n0 + tx * 8 + q * 4] = o;
    }
  }
}

__global__ void fc_kernel(const float* __restrict__ hfinal,
                          const float* __restrict__ fc_w,
                          const float* __restrict__ fc_b,
                          float* __restrict__ out)
{
  const int tid = threadIdx.x;   // 512 threads: b = tid/4, quarter = tid%4
  const int b = tid >> 2, q = tid & 3;
  float s = 0.f;
  const float* hp = hfinal + b * 512 + q * 128;
  const float* wp = fc_w + q * 128;
  #pragma unroll 4
  for (int k = 0; k < 128; ++k) s += hp[k] * wp[k];
  s += __shfl_xor(s, 1, 64);
  s += __shfl_xor(s, 2, 64);
  if (q == 0) out[b] = s + fc_b[0];
}

extern "C" void kernel_launch(void* const* d_in, const int* in_sizes, int n_in,
                              void* d_out, int out_size, void* d_ws, size_t ws_size,
                              hipStream_t stream)
{
  const float* x     = (const float*)d_in[0];
  const float* wih0f = (const float*)d_in[1];
  const float* whh0f = (const float*)d_in[2];
  const float* bih0f = (const float*)d_in[3];
  const float* bhh0f = (const float*)d_in[4];
  const float* wih0b = (const float*)d_in[5];
  const float* whh0b = (const float*)d_in[6];
  const float* bih0b = (const float*)d_in[7];
  const float* bhh0b = (const float*)d_in[8];
  const float* wih1f = (const float*)d_in[9];
  const float* whh1f = (const float*)d_in[10];
  const float* bih1f = (const float*)d_in[11];
  const float* bhh1f = (const float*)d_in[12];
  const float* wih1b = (const float*)d_in[13];
  const float* whh1b = (const float*)d_in[14];
  const float* bih1b = (const float*)d_in[15];
  const float* bhh1b = (const float*)d_in[16];
  const float* fcw   = (const float*)d_in[17];
  const float* fcb   = (const float*)d_in[18];

  const size_t n_out0 = (size_t)T_ * B_ * 512;
  const size_t nring0 = 64ull * 2 * 4 * 256;
  const size_t nring1 = 64ull * 2 * 2 * 256;

  int CH = 0;
  const int cands[4] = {64, 32, 16, 8};
  const size_t fixedf = n_out0 + (size_t)B_ * 1024 + 2 * (size_t)B_ * 256
                      + (size_t)B_ * 512;
  for (int i = 0; i < 4; ++i) {
    const size_t need = 4 * (fixedf + (size_t)cands[i] * B_ * 1024)
                      + 8 * (nring0 + nring1);
    if (need <= ws_size) { CH = cands[i]; break; }
  }
  if (!CH) return;

  float* out0 = (float*)d_ws;
  float* xg1  = out0 + n_out0;                      // [CH][B][1024]
  float* xg1b = xg1 + (size_t)CH * B_ * 1024;       // [1][B][1024]
  float* hst1 = xg1b + (size_t)B_ * 1024;
  float* cst1 = hst1 + (size_t)B_ * 256;
  float* hfin = cst1 + (size_t)B_ * 256;            // [B][512]
  ull*  ring0 = (ull*)(hfin + (size_t)B_ * 512);
  ull*  ring1 = ring0 + nring0;

  hipMemsetAsync(ring0, 0, (nring0 + nring1) * sizeof(ull), stream);

  // Layer 0: 2 dirs x 32 groups (BB=4) x 4 j-split WGs = 256 WGs, 1/CU.
  recur<4, true><<<dim3(256), dim3(256), 0, stream>>>(
      whh0f, whh0b, wih0f, wih0b, bih0f, bhh0f, bih0b, bhh0b,
      x, nullptr, out0, nullptr, nullptr, nullptr, ring0,
      /*ngroup*/32, /*dir_base*/0, /*nsteps*/T_, /*step_base*/0,
      /*first*/1, /*save*/0, /*lastW*/0);

  // Layer 1 backward: only t=T-1 needed -> one xg row-block + one step.
  xg_gemm<<<dim3(1, 8), dim3(256), 0, stream>>>(
      out0 + (size_t)(T_ - 1) * B_ * 512, wih1b, bih1b, bhh1b, xg1b);
  recur<2, false><<<dim3(256), dim3(256), 0, stream>>>(
      whh1f, whh1b, nullptr, nullptr, nullptr, nullptr, nullptr, nullptr,
      nullptr, xg1b, nullptr, hst1, cst1, hfin, ring1,
      /*ngroup*/64, /*dir_base*/1, /*nsteps*/1, /*step_base*/0,
      /*first*/1, /*save*/0, /*lastW*/1);

  // Layer 1 forward: chunked xg GEMM + recurrence (64 groups BB=2 x 4 WGs).
  const int nch = T_ / CH;
  for (int c = 0; c < nch; ++c) {
    xg_gemm<<<dim3(CH, 8), dim3(256), 0, stream>>>(
        out0 + (size_t)c * CH * B_ * 512, wih1f, bih1f, bhh1f, xg1);
    recur<2, false><<<dim3(256), dim3(256), 0, stream>>>(
        whh1f, whh1b, nullptr, nullptr, nullptr, nullptr, nullptr, nullptr,
        nullptr, xg1, nullptr, hst1, cst1, hfin, ring1,
        /*ngroup*/64, /*dir_base*/0, /*nsteps*/CH, /*step_base*/c * CH,
        /*first*/c == 0 ? 1 : 0, /*save*/1, /*lastW*/c == nch - 1 ? 1 : 0);
  }

  fc_kernel<<<dim3(1), dim3(512), 0, stream>>>(hfin, fcw, fcb, (float*)d_out);
}